// Round 6
// baseline (439.071 us; speedup 1.0000x reference)
//
#include <hip/hip_runtime.h>
#include <math.h>

#define NH   16
#define SEQ  1024
#define DIM  64
#define MUV  (1.0f/1024.0f)

typedef __attribute__((ext_vector_type(8))) short bf16x8;
typedef __attribute__((ext_vector_type(4))) float f32x4;

__device__ __forceinline__ float frcp(float x){ return __builtin_amdgcn_rcpf(x); }
__device__ __forceinline__ float bf2f(unsigned short u){
  union { unsigned int i; float f; } v; v.i = ((unsigned int)u) << 16; return v.f;
}
__device__ __forceinline__ unsigned short f2bf(float f){
  union { float f; unsigned int i; } v; v.f = f;
  return (unsigned short)((v.i + 0x7FFFu + ((v.i >> 16) & 1u)) >> 16);
}

// ---------------- prep: Q,K -> bf16 linear; V -> bf16 transposed Vt[h][d][j] ----------------
__global__ __launch_bounds__(256) void prep_kernel(const float* __restrict__ Q,
                                                   const float* __restrict__ K,
                                                   const float* __restrict__ V,
                                                   unsigned short* __restrict__ Qbf,
                                                   unsigned short* __restrict__ Kbf,
                                                   unsigned short* __restrict__ Vt) {
  __shared__ float Vsh[64][68];
  const int h = blockIdx.y, ck = blockIdx.x, t = threadIdx.x;
  const int r = t >> 2, cp = (t & 3) * 16;
  const size_t gbase = ((size_t)h * SEQ + ck * 64 + r) * DIM + cp;
  {
    union { unsigned short u[16]; uint4 q[2]; } pk;
#pragma unroll
    for (int k = 0; k < 4; k++){
      const float4 v = *(const float4*)(Q + gbase + k * 4);
      pk.u[k*4+0]=f2bf(v.x); pk.u[k*4+1]=f2bf(v.y); pk.u[k*4+2]=f2bf(v.z); pk.u[k*4+3]=f2bf(v.w);
    }
    *(uint4*)(Qbf + gbase) = pk.q[0];
    *(uint4*)(Qbf + gbase + 8) = pk.q[1];
  }
  {
    union { unsigned short u[16]; uint4 q[2]; } pk;
#pragma unroll
    for (int k = 0; k < 4; k++){
      const float4 v = *(const float4*)(K + gbase + k * 4);
      pk.u[k*4+0]=f2bf(v.x); pk.u[k*4+1]=f2bf(v.y); pk.u[k*4+2]=f2bf(v.z); pk.u[k*4+3]=f2bf(v.w);
    }
    *(uint4*)(Kbf + gbase) = pk.q[0];
    *(uint4*)(Kbf + gbase + 8) = pk.q[1];
  }
  {
#pragma unroll
    for (int k = 0; k < 4; k++)
      *(float4*)&Vsh[r][cp + k * 4] = *(const float4*)(V + gbase + k * 4);
    __syncthreads();
    const int dd = t >> 2, jp = (t & 3) * 16;
    union { unsigned short u[16]; uint4 q[2]; } pk;
#pragma unroll
    for (int k = 0; k < 16; k++) pk.u[k] = f2bf(Vsh[jp + k][dd]);
    unsigned short* dst = Vt + ((size_t)h * DIM + dd) * SEQ + ck * 64 + jp;
    *(uint4*)dst       = pk.q[0];
    *(uint4*)(dst + 8) = pk.q[1];
  }
}

// ---------------- one Sinkhorn iteration: register-resident Kexp, atomic col sums ----------------
// grid (64 chunks, 16 heads) = 1024 blocks, 16 rows each, 4 blocks/CU.
__global__ __launch_bounds__(256, 4)
void sink_rc(const unsigned short* __restrict__ Qbf,
             const unsigned short* __restrict__ Kbf,
             const float* __restrict__ cprev,
             float* __restrict__ cnext,
             float* __restrict__ zer,
             float* __restrict__ avg,
             int first)
{
  __shared__ float bsh[1024];
  __shared__ float csh[1024];
  __shared__ float rsum[4][16];
  __shared__ float ash[16];
  const int h = blockIdx.y, ch = blockIdx.x, r0 = ch * 16, t = threadIdx.x;
  const int lane = t & 63, w = t >> 6, fr = lane & 15, fq = lane >> 4;

  if (t < 16) zer[h * SEQ + ch * 16 + t] = 0.f;   // pre-zero next iteration's accum buffer

  if (first){
    *(float4*)&bsh[t * 4] = make_float4(1.f, 1.f, 1.f, 1.f);
  } else {
    const float4 c4 = *(const float4*)(cprev + h * SEQ + t * 4);
    *(float4*)&bsh[t * 4] = make_float4(MUV * frcp(c4.x), MUV * frcp(c4.y),
                                        MUV * frcp(c4.z), MUV * frcp(c4.w));
  }
  __syncthreads();

  const unsigned short* qp = Qbf + ((size_t)(h * SEQ) + r0 + fr) * DIM + fq * 8;
  const bf16x8 qa0 = *(const bf16x8*)qp;
  const bf16x8 qa1 = *(const bf16x8*)(qp + 32);

  unsigned int kx0[16], kx1[16];
  float rp0 = 0.f, rp1 = 0.f, rp2 = 0.f, rp3 = 0.f;

#pragma unroll
  for (int cc = 0; cc < 16; cc++){
    const int c0 = cc * 64 + w * 16;
    const unsigned short* kp = Kbf + ((size_t)(h * SEQ) + c0 + fr) * DIM + fq * 8;
    const bf16x8 kb0 = *(const bf16x8*)kp;
    const bf16x8 kb1 = *(const bf16x8*)(kp + 32);
    f32x4 a = {0.f, 0.f, 0.f, 0.f};
    a = __builtin_amdgcn_mfma_f32_16x16x32_bf16(qa0, kb0, a, 0, 0, 0);
    a = __builtin_amdgcn_mfma_f32_16x16x32_bf16(qa1, kb1, a, 0, 0, 0);
    const float bc = bsh[c0 + fr];
    const float k0 = __expf(-0.125f * __expf(a[0]));
    const float k1 = __expf(-0.125f * __expf(a[1]));
    const float k2 = __expf(-0.125f * __expf(a[2]));
    const float k3 = __expf(-0.125f * __expf(a[3]));
    rp0 += k0 * bc; rp1 += k1 * bc; rp2 += k2 * bc; rp3 += k3 * bc;
    kx0[cc] = (unsigned int)f2bf(k0) | ((unsigned int)f2bf(k1) << 16);
    kx1[cc] = (unsigned int)f2bf(k2) | ((unsigned int)f2bf(k3) << 16);
  }

  // row sums: reduce across the 16 fr lanes
#pragma unroll
  for (int m = 1; m <= 8; m <<= 1){
    rp0 += __shfl_xor(rp0, m); rp1 += __shfl_xor(rp1, m);
    rp2 += __shfl_xor(rp2, m); rp3 += __shfl_xor(rp3, m);
  }
  if (fr == 0){
    rsum[w][fq * 4 + 0] = rp0; rsum[w][fq * 4 + 1] = rp1;
    rsum[w][fq * 4 + 2] = rp2; rsum[w][fq * 4 + 3] = rp3;
  }
  __syncthreads();
  if (t < 16){
    const float rs = rsum[0][t] + rsum[1][t] + rsum[2][t] + rsum[3][t];
    const float a_ = MUV * frcp(rs);
    ash[t] = a_;
    avg[h * SEQ + r0 + t] = a_;   // last iteration's value wins
  }
  __syncthreads();

  // col partials from register-resident Kexp
  const float a0 = ash[fq * 4 + 0], a1 = ash[fq * 4 + 1];
  const float a2 = ash[fq * 4 + 2], a3 = ash[fq * 4 + 3];
#pragma unroll
  for (int cc = 0; cc < 16; cc++){
    float cp = a0 * bf2f((unsigned short)kx0[cc]) + a1 * bf2f((unsigned short)(kx0[cc] >> 16))
             + a2 * bf2f((unsigned short)kx1[cc]) + a3 * bf2f((unsigned short)(kx1[cc] >> 16));
    cp += __shfl_xor(cp, 16);
    cp += __shfl_xor(cp, 32);
    if (lane < 16) csh[cc * 64 + w * 16 + fr] = cp;
  }
  __syncthreads();
  {
    const float4 c4 = *(const float4*)&csh[t * 4];
    float* dst = cnext + h * SEQ + t * 4;
    atomicAdd(dst + 0, c4.x); atomicAdd(dst + 1, c4.y);
    atomicAdd(dst + 2, c4.z); atomicAdd(dst + 3, c4.w);
  }
}

// ---------------- final: recompute, direct-store fp32 p, PV via MFMA ----------------
// grid (64 chunks, 16 heads) = 1024 blocks, 16 rows each, 4 blocks/CU.
__global__ __launch_bounds__(256, 4)
void final_fused(const unsigned short* __restrict__ Qbf,
                 const unsigned short* __restrict__ Kbf,
                 const unsigned short* __restrict__ Vt,
                 const float* __restrict__ cfin,
                 const float* __restrict__ avg,
                 float* __restrict__ Pmat,
                 float* __restrict__ out)
{
  __shared__ unsigned short Psh[16 * 1024];   // 32KB bf16 p, row stride 2048B, XOR-swizzled
  __shared__ float bsh[1024];
  __shared__ float ash[16];
  const int h = blockIdx.y, ch = blockIdx.x, r0 = ch * 16, t = threadIdx.x;
  const int lane = t & 63, w = t >> 6, fr = lane & 15, fq = lane >> 4;

  {
    const float4 c4 = *(const float4*)(cfin + h * SEQ + t * 4);
    *(float4*)&bsh[t * 4] = make_float4(MUV * frcp(c4.x), MUV * frcp(c4.y),
                                        MUV * frcp(c4.z), MUV * frcp(c4.w));
  }
  if (t < 16) ash[t] = 1024.f * avg[h * SEQ + r0 + t];
  __syncthreads();

  const float ar0 = ash[fq * 4 + 0], ar1 = ash[fq * 4 + 1];
  const float ar2 = ash[fq * 4 + 2], ar3 = ash[fq * 4 + 3];

  const unsigned short* qp = Qbf + ((size_t)(h * SEQ) + r0 + fr) * DIM + fq * 8;
  const bf16x8 qa0 = *(const bf16x8*)qp;
  const bf16x8 qa1 = *(const bf16x8*)(qp + 32);

#pragma unroll
  for (int cc = 0; cc < 16; cc++){
    const int c0 = cc * 64 + w * 16;
    const unsigned short* kp = Kbf + ((size_t)(h * SEQ) + c0 + fr) * DIM + fq * 8;
    const bf16x8 kb0 = *(const bf16x8*)kp;
    const bf16x8 kb1 = *(const bf16x8*)(kp + 32);
    f32x4 a = {0.f, 0.f, 0.f, 0.f};
    a = __builtin_amdgcn_mfma_f32_16x16x32_bf16(qa0, kb0, a, 0, 0, 0);
    a = __builtin_amdgcn_mfma_f32_16x16x32_bf16(qa1, kb1, a, 0, 0, 0);
    const float bc = bsh[c0 + fr];
    const float p0 = ar0 * bc * __expf(-0.125f * __expf(a[0]));
    const float p1 = ar1 * bc * __expf(-0.125f * __expf(a[1]));
    const float p2 = ar2 * bc * __expf(-0.125f * __expf(a[2]));
    const float p3 = ar3 * bc * __expf(-0.125f * __expf(a[3]));
    // fp32 p, direct global store (4 rows x 64B segments per wave-store)
    float* pg = Pmat + ((size_t)(h * SEQ) + r0 + fq * 4) * SEQ + c0 + fr;
    pg[0 * SEQ] = p0; pg[1 * SEQ] = p1; pg[2 * SEQ] = p2; pg[3 * SEQ] = p3;
    // bf16 p into LDS for the PV A-fragments
    const int col2 = (c0 + fr) * 2;
    const int row0 = fq * 4;
    *(unsigned short*)((char*)Psh + (row0    ) * 2048 + (col2 ^ (((row0    ) & 7) << 4))) = f2bf(p0);
    *(unsigned short*)((char*)Psh + (row0 + 1) * 2048 + (col2 ^ (((row0 + 1) & 7) << 4))) = f2bf(p1);
    *(unsigned short*)((char*)Psh + (row0 + 2) * 2048 + (col2 ^ (((row0 + 2) & 7) << 4))) = f2bf(p2);
    *(unsigned short*)((char*)Psh + (row0 + 3) * 2048 + (col2 ^ (((row0 + 3) & 7) << 4))) = f2bf(p3);
  }
  __syncthreads();

  // PV: A = p (bf16 from Psh), B = Vt direct 16B loads
  f32x4 o = {0.f, 0.f, 0.f, 0.f};
  const unsigned short* vp = Vt + ((size_t)h * DIM + w * 16 + fr) * SEQ;
  const char* pr = (const char*)Psh + fr * 2048;
  const int sw = (fr & 7) << 4;
#pragma unroll 8
  for (int jc = 0; jc < 32; jc++){
    const int jb = jc * 32 + fq * 8;
    const bf16x8 pa = *(const bf16x8*)(pr + ((jb * 2) ^ sw));
    const bf16x8 vb = *(const bf16x8*)(vp + jb);
    o = __builtin_amdgcn_mfma_f32_16x16x32_bf16(pa, vb, o, 0, 0, 0);
  }

  float* og = out + ((size_t)(h * SEQ) + r0 + fq * 4) * DIM + w * 16 + fr;
  og[0 * DIM] = o[0]; og[1 * DIM] = o[1]; og[2 * DIM] = o[2]; og[3 * DIM] = o[3];
}

extern "C" void kernel_launch(void* const* d_in, const int* in_sizes, int n_in,
                              void* d_out, int out_size, void* d_ws, size_t ws_size,
                              hipStream_t stream) {
  (void)in_sizes; (void)n_in; (void)out_size; (void)ws_size;
  const float* Q = (const float*)d_in[0];
  const float* K = (const float*)d_in[1];
  const float* V = (const float*)d_in[2];
  float* out  = (float*)d_out;
  float* Pmat = out + (size_t)NH * SEQ * DIM;

  unsigned short* Qbf = (unsigned short*)d_ws;                 // 2 MB
  unsigned short* Kbf = Qbf + (size_t)NH * SEQ * DIM;          // 2 MB
  unsigned short* Vt  = Kbf + (size_t)NH * SEQ * DIM;          // 2 MB
  float* cbuf = (float*)(Vt + (size_t)NH * SEQ * DIM);         // 3 x 64 KB rotating c-sums
  float* avg  = cbuf + (size_t)3 * NH * SEQ;                   // 64 KB

  prep_kernel<<<dim3(16, 16), 256, 0, stream>>>(Q, K, V, Qbf, Kbf, Vt);
  hipMemsetAsync(cbuf + (size_t)NH * SEQ, 0, (size_t)NH * SEQ * sizeof(float), stream);
  for (int it = 0; it < 10; it++){
    float* crd = cbuf + (size_t)(it % 3) * NH * SEQ;
    float* cac = cbuf + (size_t)((it + 1) % 3) * NH * SEQ;
    float* czr = cbuf + (size_t)((it + 2) % 3) * NH * SEQ;
    sink_rc<<<dim3(64, 16), 256, 0, stream>>>(Qbf, Kbf, crd, cac, czr, avg, it == 0 ? 1 : 0);
  }
  float* cfin = cbuf + (size_t)((10) % 3) * NH * SEQ;  // = cbuf + 1*NH*SEQ
  final_fused<<<dim3(64, 16), 256, 0, stream>>>(Qbf, Kbf, Vt, cfin, avg, Pmat, out);
}